// Round 1
// baseline (510.557 us; speedup 1.0000x reference)
//
#include <hip/hip_runtime.h>
#include <math.h>

// Problem constants (fixed by setup_inputs)
constexpr int NB = 8;    // batch
constexpr int NC = 64;   // in channels
constexpr int NO = 64;   // out channels
constexpr int NH = 64;
constexpr int NW = 64;
constexpr int NA = 4;    // spatial atoms
constexpr int NKK = 9;   // K*K taps
// f = ((o*NA + a)*NKK + k), w_gen[f][c], row-major (2304 x 64)

// Block: 256 threads = 4 waves. lane = w. Each wave handles one o-group of 8 o's.
// blockIdx.x in [0, NB*NH): b = bx/NH, h = bx%NH
// blockIdx.y in [0, 2): o-half. og = blockIdx.y*4 + wave (0..7), o = og*8 + oi.
__global__ __launch_bounds__(256, 4)
void acda_f32_kernel(const float* __restrict__ x,
                     const float* __restrict__ w_gen,
                     const float* __restrict__ b_gen,
                     const float* __restrict__ pos_enc,
                     float* __restrict__ out) {
    const int lane = threadIdx.x & 63;
    const int wave = __builtin_amdgcn_readfirstlane(threadIdx.x >> 6);
    const int bx = blockIdx.x;
    const int b  = bx >> 6;     // / NH
    const int h  = bx & 63;     // % NH
    const int w  = lane;
    const int og = blockIdx.y * 4 + wave;   // 0..7

    // ---- load this location's input vector x[b,:,h,w] into registers ----
    const float* xp = x + ((size_t)b * NC * NH * NW) + (size_t)h * NW + w;
    float xv[NC];
#pragma unroll
    for (int c = 0; c < NC; ++c) xv[c] = xp[(size_t)c * NH * NW];

    // ---- spatial attention weights att[a] = exp(-||grid - pos||^2) ----
    // grid[h,w] = (xs[w], ys[h]), linspace(-1,1,64) => step 2/63
    const float gx = -1.0f + (2.0f / 63.0f) * (float)w;
    const float gy = -1.0f + (2.0f / 63.0f) * (float)h;
    float att[NA];
#pragma unroll
    for (int a = 0; a < NA; ++a) {
        float dx = gx - pos_enc[2 * a + 0];
        float dy = gy - pos_enc[2 * a + 1];
        att[a] = expf(-(dx * dx + dy * dy));
    }

    // ---- main loop over this thread's 8 output channels ----
    for (int oi = 0; oi < 8; ++oi) {
        const int o = og * 8 + oi;
        const float* wbase = w_gen + (size_t)o * NA * NKK * NC;  // 36 rows of 64
        const float* bbase = b_gen + (size_t)o * NA * NKK;

        float comb[NKK];
#pragma unroll
        for (int k = 0; k < NKK; ++k) comb[k] = 0.0f;

#pragma unroll
        for (int a = 0; a < NA; ++a) {
            const float atv = att[a];
#pragma unroll
            for (int k = 0; k < NKK; ++k) {
                const float* wr = wbase + (size_t)(a * NKK + k) * NC;
                float acc0 = 0.0f, acc1 = 0.0f, acc2 = 0.0f, acc3 = 0.0f;
#pragma unroll
                for (int c = 0; c < NC; c += 4) {
                    acc0 = fmaf(wr[c + 0], xv[c + 0], acc0);
                    acc1 = fmaf(wr[c + 1], xv[c + 1], acc1);
                    acc2 = fmaf(wr[c + 2], xv[c + 2], acc2);
                    acc3 = fmaf(wr[c + 3], xv[c + 3], acc3);
                }
                float v = (acc0 + acc1) + (acc2 + acc3) + bbase[a * NKK + k];
                v = v > 0.0f ? v : 0.0f;                 // ReLU
                comb[k] = fmaf(atv, v, comb[k]);          // sum over atoms
            }
        }

        // ---- epilogue: 3x3 unfolded-patch weighted sum (channel o of x) ----
        float result = 0.0f;
        const float* xo = x + ((size_t)b * NC + o) * (NH * NW);
#pragma unroll
        for (int kh = 0; kh < 3; ++kh) {
#pragma unroll
            for (int kw = 0; kw < 3; ++kw) {
                const int hh = h + kh - 1;
                const int ww = w + kw - 1;
                float p = 0.0f;
                if (hh >= 0 && hh < NH && ww >= 0 && ww < NW)
                    p = xo[hh * NW + ww];
                result = fmaf(comb[kh * 3 + kw], p, result);
            }
        }
        out[(((size_t)b * NO + o) * NH + h) * NW + w] = result;
    }
}

extern "C" void kernel_launch(void* const* d_in, const int* in_sizes, int n_in,
                              void* d_out, int out_size, void* d_ws, size_t ws_size,
                              hipStream_t stream) {
    const float* x       = (const float*)d_in[0];
    const float* w_gen   = (const float*)d_in[1];
    const float* b_gen   = (const float*)d_in[2];
    const float* pos_enc = (const float*)d_in[3];
    float* out = (float*)d_out;

    dim3 grid(NB * NH, 2);   // 512 x 2 = 1024 blocks
    dim3 block(256);
    hipLaunchKernelGGL(acda_f32_kernel, grid, block, 0, stream,
                       x, w_gen, b_gen, pos_enc, out);
}

// Round 2
// 74.206 us; speedup vs baseline: 6.8803x; 6.8803x over previous
//
#include <hip/hip_runtime.h>
#include <math.h>

constexpr int NB = 8, NC = 64, NO = 64, NH = 64, NW = 64, NA = 4, NKK = 9;

using f32x4 = __attribute__((ext_vector_type(4))) float;
using s16x8 = __attribute__((ext_vector_type(8))) short;

__device__ __forceinline__ unsigned short f2bf(float f) {
    unsigned u = __builtin_bit_cast(unsigned, f);
    unsigned r = (u + 0x7fffu + ((u >> 16) & 1u)) >> 16;
    return (unsigned short)r;
}

// Grid: 256 blocks = b(8) x h-pair(32). Block: 512 threads = 8 waves.
// Wave wv: hsub = wv>>2 (which h row), wsub = wv&3 (16-w subtile).
// MFMA 16x16x32 bf16. C layout: col = lane&15 (o-local), row = (lane>>4)*4+reg (w-local).
// A/B frags: lane reads 8 contiguous c at c0 = (lane>>4)*8 + Kh*32.
__global__ __launch_bounds__(512, 2) __attribute__((amdgpu_waves_per_eu(2, 2)))
void acda_mfma_kernel(const float* __restrict__ x,
                      const float* __restrict__ w_gen,
                      const float* __restrict__ b_gen,
                      const float* __restrict__ pos_enc,
                      float* __restrict__ out) {
    __shared__ unsigned short Abuf[2 * 64 * 64];   // [hsub][w][c] bf16, XOR-swizzled (16 KB)
    __shared__ unsigned short Bbuf[2][64 * 64];    // dbuf [o][c] bf16, XOR-swizzled (16 KB)
    __shared__ float Patch[4 * 66 * 66];           // [hhi][wwi][66: 64 o + 2 pad] f32 (69.7 KB)
    __shared__ float BiasL[2304];                  // 9.2 KB

    const int tid  = threadIdx.x;
    const int lane = tid & 63;
    const int wv   = tid >> 6;          // 0..7
    const int hsub = wv >> 2, wsub = wv & 3;
    const int c0   = lane & 15, q = lane >> 4;

    const int b     = blockIdx.x >> 5;
    const int hbase = (blockIdx.x & 31) << 1;
    const int h     = hbase + hsub;

    const size_t xB = (size_t)b * NC * NH * NW;

    // ---------------- prologue staging ----------------
    // A: x[b, c, hbase+hs, w] -> Abuf[hs][w][c] (transpose to loc-major, bf16, swizzled)
    {
        const int w = lane;
        const int oct = wv;  // c-octet
#pragma unroll
        for (int hs = 0; hs < 2; ++hs) {
            s16x8 pk;
#pragma unroll
            for (int j = 0; j < 8; ++j)
                pk[j] = (short)f2bf(x[xB + (size_t)(oct * 8 + j) * (NH * NW) +
                                      (size_t)(hbase + hs) * NW + w]);
            const int byte = hs * 8192 + w * 128 + ((oct * 16) ^ ((w & 7) << 4));
            *reinterpret_cast<s16x8*>(reinterpret_cast<char*>(Abuf) + byte) = pk;
        }
    }
    // patch: x[b, o, hbase-1+hhi, ww] f32 -> Patch[hhi][ww+1][o], zero halo
    {
#pragma unroll 4
        for (int i = 0; i < 32; ++i) {
            const int row = wv * 32 + i;       // 0..255
            const int hhi = row >> 6;          // 0..3
            const int o   = row & 63;
            const int hh  = hbase - 1 + hhi;
            float v = 0.0f;
            if (hh >= 0 && hh < NH) v = x[xB + (size_t)o * (NH * NW) + hh * NW + lane];
            Patch[(hhi * 66 + (lane + 1)) * 66 + o] = v;
            if (lane < 2) Patch[(hhi * 66 + (lane ? 65 : 0)) * 66 + o] = 0.0f;
        }
    }
    // bias
    for (int i = tid; i < NO * NA * NKK; i += 512) BiasL[i] = b_gen[i];

    // B-stage: w_gen rows f=(o*4+a)*9+k for o=0..63 -> Bbuf[buf][o][c] bf16 swizzled
    auto stageB = [&](int a, int k, int buf) {
        const int o = tid >> 3;               // 0..63
        const int cseg = (tid & 7) * 8;       // 0..56
        const int f = (o * NA + a) * NKK + k;
        const float4* src = reinterpret_cast<const float4*>(w_gen + (size_t)f * NC + cseg);
        float4 v0 = src[0], v1 = src[1];
        s16x8 pk;
        pk[0] = (short)f2bf(v0.x); pk[1] = (short)f2bf(v0.y);
        pk[2] = (short)f2bf(v0.z); pk[3] = (short)f2bf(v0.w);
        pk[4] = (short)f2bf(v1.x); pk[5] = (short)f2bf(v1.y);
        pk[6] = (short)f2bf(v1.z); pk[7] = (short)f2bf(v1.w);
        const int byte = o * 128 + ((cseg * 2) ^ ((o & 7) << 4));
        *reinterpret_cast<s16x8*>(reinterpret_cast<char*>(Bbuf[buf]) + byte) = pk;
    };
    stageB(0, 0, 0);
    __syncthreads();

    // ---------------- A fragments (registers, reused for all 144 tiles) ----------------
    s16x8 afrag[2];
    {
        const int row = wsub * 16 + c0;       // w-loc within this hsub
#pragma unroll
        for (int kh2 = 0; kh2 < 2; ++kh2) {
            const int byte = hsub * 8192 + row * 128 + ((kh2 * 64 + q * 16) ^ ((row & 7) << 4));
            afrag[kh2] = *reinterpret_cast<s16x8*>(reinterpret_cast<char*>(Abuf) + byte);
        }
    }

    // att inputs
    float gxr[4];
    const float gy = -1.0f + (2.0f / 63.0f) * (float)h;
#pragma unroll
    for (int r = 0; r < 4; ++r)
        gxr[r] = -1.0f + (2.0f / 63.0f) * (float)(wsub * 16 + q * 4 + r);

    float outacc[4][4] = {};  // [oc][reg]

    const float* pbase0 = Patch + (hsub * 66 + wsub * 16 + q * 4) * 66 + c0;

    int buf = 0;
    for (int a = 0; a < NA; ++a) {
        const float px = pos_enc[2 * a], py = pos_enc[2 * a + 1];
        float att[4];
#pragma unroll
        for (int r = 0; r < 4; ++r) {
            const float dx = gxr[r] - px, dy = gy - py;
            att[r] = __expf(-(dx * dx + dy * dy));
        }
        int kh = 0, kw = 0;
        for (int k = 0; k < NKK; ++k) {
            // stage next (a,k) into other buffer
            const int t = a * NKK + k;
            if (t < NA * NKK - 1) {
                int kn = k + 1, an = a;
                if (kn == NKK) { kn = 0; an = a + 1; }
                stageB(an, kn, buf ^ 1);
            }
            const unsigned short* Bb = Bbuf[buf];
            const float* pb = pbase0 + (kh * 66 + kw) * 66;
            const int bias0 = (c0 * NA + a) * NKK + k;
#pragma unroll
            for (int oc = 0; oc < 4; ++oc) {
                const int fcol = oc * 16 + c0;
                const int bbase = fcol * 128;
                const int sw = (fcol & 7) << 4;
                s16x8 bfr0 = *reinterpret_cast<const s16x8*>(
                    reinterpret_cast<const char*>(Bb) + bbase + ((q * 16) ^ sw));
                s16x8 bfr1 = *reinterpret_cast<const s16x8*>(
                    reinterpret_cast<const char*>(Bb) + bbase + ((64 + q * 16) ^ sw));
                const float bb = BiasL[bias0 + oc * 576];
                f32x4 acc = {bb, bb, bb, bb};
                acc = __builtin_amdgcn_mfma_f32_16x16x32_bf16(afrag[0], bfr0, acc, 0, 0, 0);
                acc = __builtin_amdgcn_mfma_f32_16x16x32_bf16(afrag[1], bfr1, acc, 0, 0, 0);
#pragma unroll
                for (int r = 0; r < 4; ++r) {
                    const float v = fmaxf(acc[r], 0.0f) * att[r];
                    const float p = pb[oc * 16 + r * 66];
                    outacc[oc][r] = fmaf(v, p, outacc[oc][r]);
                }
            }
            __syncthreads();
            buf ^= 1;
            if (++kw == 3) { kw = 0; ++kh; }
        }
    }

    // ---------------- store ----------------
#pragma unroll
    for (int oc = 0; oc < 4; ++oc) {
        const int o = oc * 16 + c0;
#pragma unroll
        for (int r = 0; r < 4; ++r) {
            const int w = wsub * 16 + q * 4 + r;
            out[(((size_t)b * NO + o) * NH + h) * NW + w] = outacc[oc][r];
        }
    }
}

extern "C" void kernel_launch(void* const* d_in, const int* in_sizes, int n_in,
                              void* d_out, int out_size, void* d_ws, size_t ws_size,
                              hipStream_t stream) {
    const float* x       = (const float*)d_in[0];
    const float* w_gen   = (const float*)d_in[1];
    const float* b_gen   = (const float*)d_in[2];
    const float* pos_enc = (const float*)d_in[3];
    float* out = (float*)d_out;

    dim3 grid(NB * 32);   // 256 workgroups
    dim3 block(512);
    hipLaunchKernelGGL(acda_mfma_kernel, grid, block, 0, stream,
                       x, w_gen, b_gen, pos_enc, out);
}

// Round 4
// 29.264 us; speedup vs baseline: 17.4469x; 2.5358x over previous
//
#include <hip/hip_runtime.h>
#include <math.h>

constexpr int NB = 8, NC = 64, NO = 64, NH = 64, NW = 64, NA = 4, NKK = 9;

using f32x4 = __attribute__((ext_vector_type(4))) float;
using s16x8 = __attribute__((ext_vector_type(8))) short;

__device__ __forceinline__ unsigned short f2bf(float f) {
    unsigned u = __builtin_bit_cast(unsigned, f);
    return (unsigned short)((u + 0x7fffu + ((u >> 16) & 1u)) >> 16);
}
__device__ __forceinline__ float bf2f(unsigned short s) {
    unsigned u = ((unsigned)s) << 16;
    return __builtin_bit_cast(float, u);
}

// Grid: 512 = b(8) x hpair(32) x osub(2). Block: 512 thr = 8 waves.
// Block tile: 2 h-rows x 64 w (128 locs) x 32 o's (obase = osub*32).
// Wave wv: ofrag = wv&1 (16 o's), ltile = wv>>1 -> hrow = ltile>>1, whalf = ltile&1.
// Each wave: 2 n-tiles (16 w each) x 1 o-frag; MFMA A = weights (rows=o), B = x (cols=w).
// D layout: row (o_local) = (lane>>4)*4 + reg, col (w) = lane&15  -> coalesced stores.
__global__ __launch_bounds__(512, 4)
void acda_kernel(const float* __restrict__ x, const float* __restrict__ w_gen,
                 const float* __restrict__ b_gen, const float* __restrict__ pos_enc,
                 float* __restrict__ out)
{
    __shared__ unsigned short Xs[128 * 64];          // 16 KB [loc][c] bf16, XOR-swizzled
    __shared__ unsigned short Wb[2][2][32 * 64];     // 16 KB dbuf x 2taps [o_l][c] bf16, swizzled
    __shared__ unsigned short Patch[4 * 66 * 36];    // 19 KB [hhi][wwi][o_l(32)+pad4] bf16
    __shared__ float BiasL[36 * 32];                 // 4.6 KB [tap][o_l]

    const int tid  = threadIdx.x;
    const int lane = tid & 63;
    const int wv   = tid >> 6;
    const int c0   = lane & 15, q = lane >> 4;
    const int ofrag = wv & 1;
    const int ltile = wv >> 1;
    const int hrow = ltile >> 1, whalf = ltile & 1;

    const int bx    = blockIdx.x;
    const int osub  = bx & 1;
    const int hp    = (bx >> 1) & 31;
    const int b     = bx >> 6;
    const int hbase = hp * 2;
    const int obase = osub * 32;

    const size_t xB = (size_t)b * NC * NH * NW;

    // ---- stage Xs: x[b, c, hbase+hs, w] -> Xs[loc = hs*64+w][c] (bf16, swizzled) ----
    {
        const int w = lane, oct = wv;
        for (int hs = 0; hs < 2; ++hs) {
            s16x8 pk;
#pragma unroll
            for (int j = 0; j < 8; ++j)
                pk[j] = (short)f2bf(x[xB + (size_t)(oct * 8 + j) * (NH * NW) + (hbase + hs) * NW + w]);
            const int loc  = hs * 64 + w;
            const int byte = loc * 128 + ((oct * 16) ^ ((loc & 7) << 4));
            *reinterpret_cast<s16x8*>(reinterpret_cast<char*>(Xs) + byte) = pk;
        }
    }
    // ---- stage Patch: x[b, obase+o_l, hbase-1+hhi, ww] -> Patch[hhi][ww+1][o_l], bf16 ----
    {
        const int o_l = tid >> 4, i4 = (tid & 15) * 4;
        const float* xo = x + xB + (size_t)(obase + o_l) * (NH * NW);
#pragma unroll
        for (int hhi = 0; hhi < 4; ++hhi) {
            const int hh = hbase - 1 + hhi;
            float4 v = {0.f, 0.f, 0.f, 0.f};
            if (hh >= 0 && hh < NH) v = *reinterpret_cast<const float4*>(xo + hh * NW + i4);
            unsigned short* p = Patch + (hhi * 66 + i4 + 1) * 36 + o_l;
            p[0 * 36] = f2bf(v.x); p[1 * 36] = f2bf(v.y);
            p[2 * 36] = f2bf(v.z); p[3 * 36] = f2bf(v.w);
        }
        if (tid < 256) {   // zero w-halo columns (wwi = 0 and 65)
            const int hhi = tid >> 6, side = (tid >> 5) & 1, ol2 = tid & 31;
            Patch[(hhi * 66 + (side ? 65 : 0)) * 36 + ol2] = 0;
        }
    }
    // ---- stage bias: BiasL[tap][o_l] = b_gen[(obase+o_l)*36 + tap] ----
    for (int idx = tid; idx < 36 * 32; idx += 512) {
        const int t = idx >> 5, o_l = idx & 31;
        BiasL[t * 32 + o_l] = b_gen[(obase + o_l) * 36 + t];
    }
    // ---- W stage: 2 taps (tap0, tap0+1) into Wb[buf][0/1], 16B/thread ----
    auto stageW2 = [&](int tap0, int buf) {
        const int half = tid >> 8;            // which tap
        const int tt   = tid & 255;
        const int o_l  = tt >> 3, cs = (tt & 7) * 8;
        const int f    = (obase + o_l) * 36 + tap0 + half;
        const float* src = w_gen + (size_t)f * NC + cs;
        float4 v0 = *reinterpret_cast<const float4*>(src);
        float4 v1 = *reinterpret_cast<const float4*>(src + 4);
        s16x8 pk;
        pk[0] = f2bf(v0.x); pk[1] = f2bf(v0.y); pk[2] = f2bf(v0.z); pk[3] = f2bf(v0.w);
        pk[4] = f2bf(v1.x); pk[5] = f2bf(v1.y); pk[6] = f2bf(v1.z); pk[7] = f2bf(v1.w);
        const int byte = o_l * 128 + ((cs * 2) ^ ((o_l & 7) << 4));
        *reinterpret_cast<s16x8*>(reinterpret_cast<char*>(Wb[buf][half]) + byte) = pk;
    };
    stageW2(0, 0);
    __syncthreads();

    // ---- x fragments -> registers (reused for all 36 taps) ----
    s16x8 xf[2][2];
#pragma unroll
    for (int nt = 0; nt < 2; ++nt) {
        const int loc = hrow * 64 + whalf * 32 + nt * 16 + c0;
#pragma unroll
        for (int kh2 = 0; kh2 < 2; ++kh2) {
            const int byte = loc * 128 + ((kh2 * 64 + q * 16) ^ ((loc & 7) << 4));
            xf[nt][kh2] = *reinterpret_cast<s16x8*>(reinterpret_cast<char*>(Xs) + byte);
        }
    }

    const int h = hbase + hrow;
    const float gy = -1.0f + (2.0f / 63.0f) * (float)h;
    float gxn[2];
#pragma unroll
    for (int nt = 0; nt < 2; ++nt)
        gxn[nt] = -1.0f + (2.0f / 63.0f) * (float)(whalf * 32 + nt * 16 + c0);

    float pe[8];
#pragma unroll
    for (int i = 0; i < 8; ++i) pe[i] = pos_enc[i];

    const int o4 = ofrag * 16 + q * 4;     // this lane's o_local row base
    const int wrow = ofrag * 16 + c0;      // A-frag row index in Wb
    // Patch byte offsets: element ((hrow+kh)*66 + (w_local+kw))*36 + o4, *2 bytes.
    // wwi = w_local + kw  (halo: global col ww stored at wwi = ww+1; ww = w_local+kw-1)
    int pbase[2];
#pragma unroll
    for (int nt = 0; nt < 2; ++nt)
        pbase[nt] = (hrow * 66 + whalf * 32 + nt * 16 + c0) * 72 + o4 * 2;

    float outacc[2][4] = {};
    float attn[2];
    int a = 0, k = 0, buf = 0;

    for (int it = 0; it < 18; ++it) {
        if (it < 17) stageW2(2 * it + 2, buf ^ 1);
#pragma unroll
        for (int half = 0; half < 2; ++half) {
            const int tap = 2 * it + half;
            if (k == 0) {
#pragma unroll
                for (int nt = 0; nt < 2; ++nt) {
                    const float dx = gxn[nt] - pe[2 * a], dy = gy - pe[2 * a + 1];
                    attn[nt] = __expf(-(dx * dx + dy * dy));
                }
            }
            const int kh = (k * 11) >> 5, kw = k - 3 * kh;
            const unsigned short* Wt = Wb[buf][half];
            const int sw = (wrow & 7) << 4;
            s16x8 wf0 = *reinterpret_cast<const s16x8*>(
                reinterpret_cast<const char*>(Wt) + wrow * 128 + ((q * 16) ^ sw));
            s16x8 wf1 = *reinterpret_cast<const s16x8*>(
                reinterpret_cast<const char*>(Wt) + wrow * 128 + ((64 + q * 16) ^ sw));
            const f32x4 bb = *reinterpret_cast<const f32x4*>(BiasL + tap * 32 + o4);
            const int pd = (kh * 66 + kw) * 72;
#pragma unroll
            for (int nt = 0; nt < 2; ++nt) {
                f32x4 acc = bb;
                acc = __builtin_amdgcn_mfma_f32_16x16x32_bf16(wf0, xf[nt][0], acc, 0, 0, 0);
                acc = __builtin_amdgcn_mfma_f32_16x16x32_bf16(wf1, xf[nt][1], acc, 0, 0, 0);
                const ushort4 pu = *reinterpret_cast<const ushort4*>(
                    reinterpret_cast<const char*>(Patch) + pbase[nt] + pd);
                const float at = attn[nt];
                outacc[nt][0] = fmaf(fmaxf(acc[0], 0.f) * at, bf2f(pu.x), outacc[nt][0]);
                outacc[nt][1] = fmaf(fmaxf(acc[1], 0.f) * at, bf2f(pu.y), outacc[nt][1]);
                outacc[nt][2] = fmaf(fmaxf(acc[2], 0.f) * at, bf2f(pu.z), outacc[nt][2]);
                outacc[nt][3] = fmaf(fmaxf(acc[3], 0.f) * at, bf2f(pu.w), outacc[nt][3]);
            }
            if (++k == 9) { k = 0; ++a; }
        }
        __syncthreads();
        buf ^= 1;
    }

    // ---- coalesced stores: col = w (lane&15) contiguous ----
#pragma unroll
    for (int nt = 0; nt < 2; ++nt) {
        const int wcol = whalf * 32 + nt * 16 + c0;
#pragma unroll
        for (int r = 0; r < 4; ++r) {
            const int o = obase + o4 + r;
            out[(((size_t)b * NO + o) * NH + h) * NW + wcol] = outacc[nt][r];
        }
    }
}

extern "C" void kernel_launch(void* const* d_in, const int* in_sizes, int n_in,
                              void* d_out, int out_size, void* d_ws, size_t ws_size,
                              hipStream_t stream) {
    const float* x       = (const float*)d_in[0];
    const float* w_gen   = (const float*)d_in[1];
    const float* b_gen   = (const float*)d_in[2];
    const float* pos_enc = (const float*)d_in[3];
    float* out = (float*)d_out;

    dim3 grid(NB * 32 * 2);   // 512 workgroups
    dim3 block(512);
    hipLaunchKernelGGL(acda_kernel, grid, block, 0, stream,
                       x, w_gen, b_gen, pos_enc, out);
}